// Round 1
// baseline (27.070 us; speedup 1.0000x reference)
//
#include <hip/hip_runtime.h>
#include <math.h>

#define N_ROWS 256
#define NB 8732
#define NB4 2183          // NB / 4 (exact)
#define CHUNKS 4
#define G_PER_CHUNK 546   // ceil(NB4 / CHUNKS)

__device__ __forceinline__ float smooth_l1(float d) {
    float ad = fabsf(d);
    return ad < 1.0f ? 0.5f * d * d : ad - 0.5f;
}

// BCE with logits, y = 0 (used by fallback top-K path)
__device__ __forceinline__ float bce_y0(float x) {
    return fmaxf(x, 0.0f) + log1pf(expf(-fabsf(x)));
}

#define ELEMF(v, k) (((const float*)&(v))[k])
#define ELEMI(v, k) (((const int*)&(v))[k])

__global__ __launch_bounds__(256) void partial_kernel(
    const float* __restrict__ ploc, const float* __restrict__ plabel,
    const float* __restrict__ gloc, const int* __restrict__ glabel,
    const float* __restrict__ dboxes, float* __restrict__ ws) {
    const int row = blockIdx.x;
    const int chunk = blockIdx.y;
    const int tid = threadIdx.x;

    const int g0 = chunk * G_PER_CHUNK;
    const int g1 = min(g0 + G_PER_CHUNK, NB4);

    const float4* __restrict__ ploc4 = (const float4*)ploc;
    const float4* __restrict__ gloc4 = (const float4*)gloc;
    const float4* __restrict__ db4   = (const float4*)dboxes;
    const float4* __restrict__ pl4   = (const float4*)plabel;
    const int4*   __restrict__ gl4   = (const int4*)glabel;

    const int rb = row * 4 * NB4;  // base (float4 units) for [N,4,NB] tensors
    const int rs = row * NB4;      // base (float4 units) for [N,NB] tensors

    float sl1acc = 0.0f, conAll = 0.0f, conPos = 0.0f;
    int posCnt = 0;

    for (int g = g0 + tid; g < g1; g += 256) {
        float4 p0 = ploc4[rb + 0 * NB4 + g];
        float4 p1 = ploc4[rb + 1 * NB4 + g];
        float4 p2 = ploc4[rb + 2 * NB4 + g];
        float4 p3 = ploc4[rb + 3 * NB4 + g];
        float4 q0 = gloc4[rb + 0 * NB4 + g];
        float4 q1 = gloc4[rb + 1 * NB4 + g];
        float4 q2 = gloc4[rb + 2 * NB4 + g];
        float4 q3 = gloc4[rb + 3 * NB4 + g];
        float4 d0 = db4[0 * NB4 + g];
        float4 d1 = db4[1 * NB4 + g];
        float4 d2 = db4[2 * NB4 + g];
        float4 d3 = db4[3 * NB4 + g];
        int4   lb = gl4[rs + g];
        float4 px = pl4[rs + g];

#pragma unroll
        for (int k = 0; k < 4; ++k) {
            // location target vector
            float w2 = ELEMF(d2, k);
            float w3 = ELEMF(d3, k);
            float gx = (ELEMF(q0, k) - ELEMF(d0, k)) / w2;
            float gy = (ELEMF(q1, k) - ELEMF(d1, k)) / w3;
            float gw = logf(ELEMF(q2, k) / w2);
            float gh = logf(ELEMF(q3, k) / w3);
            float s = smooth_l1(ELEMF(p0, k) - gx)
                    + smooth_l1(ELEMF(p1, k) - gy)
                    + smooth_l1(ELEMF(p2, k) - gw)
                    + smooth_l1(ELEMF(p3, k) - gh);
            int lab = ELEMI(lb, k);
            float x = ELEMF(px, k);
            float con = fmaxf(x, 0.0f) - x * (float)lab + log1pf(expf(-fabsf(x)));
            conAll += con;
            if (lab > 0) {
                posCnt += 1;
                sl1acc += s;
                conPos += con;
            }
        }
    }

    // block reduction: wave64 shuffle, then LDS across 4 waves
    float v0 = sl1acc, v1 = conAll, v2 = conPos, v3 = (float)posCnt;
#pragma unroll
    for (int off = 32; off > 0; off >>= 1) {
        v0 += __shfl_down(v0, off);
        v1 += __shfl_down(v1, off);
        v2 += __shfl_down(v2, off);
        v3 += __shfl_down(v3, off);
    }
    __shared__ float sm[4][4];
    const int wid = tid >> 6, lane = tid & 63;
    if (lane == 0) {
        sm[wid][0] = v0; sm[wid][1] = v1; sm[wid][2] = v2; sm[wid][3] = v3;
    }
    __syncthreads();
    if (tid == 0) {
        float a0 = 0.f, a1 = 0.f, a2 = 0.f, a3 = 0.f;
#pragma unroll
        for (int w = 0; w < 4; ++w) {
            a0 += sm[w][0]; a1 += sm[w][1]; a2 += sm[w][2]; a3 += sm[w][3];
        }
        float* o = ws + (row * CHUNKS + chunk) * 4;
        o[0] = a0; o[1] = a1; o[2] = a2; o[3] = a3;
    }
}

__global__ __launch_bounds__(256) void final_kernel(
    const float* __restrict__ ws, const float* __restrict__ plabel,
    const int* __restrict__ glabel, float* __restrict__ out) {
    const int row = threadIdx.x;  // one thread per batch row
    float sl1 = 0.f, conAll = 0.f, conPos = 0.f, posf = 0.f;
#pragma unroll
    for (int c = 0; c < CHUNKS; ++c) {
        const float* p = ws + (row * CHUNKS + c) * 4;
        sl1 += p[0]; conAll += p[1]; conPos += p[2]; posf += p[3];
    }
    const int pos = (int)(posf + 0.5f);
    const long long K = 3LL * (long long)pos;

    float closs;
    if (pos == 0) {
        closs = 0.0f;
    } else if (K >= (long long)NB) {
        // neg_mask selects every position -> keep everything
        closs = conAll;
    } else {
        // General hard-negative-mining fallback (dead code for this data):
        // top-K negative con values. All con >= 0, so uint bit pattern order
        // == float order. Sum of top-K is tie-break independent.
        const int Ki = (int)K;
        const float* plRow = plabel + row * NB;
        const int* glRow = glabel + row * NB;
        unsigned cur = 0;
        for (int bit = 31; bit >= 0; --bit) {
            unsigned trial = cur | (1u << bit);
            int cnt = 0;
            for (int j = 0; j < NB; ++j) {
                if (glRow[j] > 0) continue;
                float con = bce_y0(plRow[j]);
                if (__float_as_uint(con) >= trial) cnt++;
            }
            if (cnt >= Ki) cur = trial;
        }
        const float thr = __uint_as_float(cur);
        int cntG = 0; float sumG = 0.f;
        for (int j = 0; j < NB; ++j) {
            if (glRow[j] > 0) continue;
            float con = bce_y0(plRow[j]);
            if (con > thr) { cntG++; sumG += con; }
        }
        closs = conPos + sumG + (float)(Ki - cntG) * thr;
    }

    float loss = (pos > 0) ? (sl1 + closs) / (float)pos : 0.0f;

    // mean over 256 rows
#pragma unroll
    for (int off = 32; off > 0; off >>= 1) loss += __shfl_down(loss, off);
    __shared__ float sm[4];
    const int wid = threadIdx.x >> 6, lane = threadIdx.x & 63;
    if (lane == 0) sm[wid] = loss;
    __syncthreads();
    if (threadIdx.x == 0) {
        float t = sm[0] + sm[1] + sm[2] + sm[3];
        out[0] = t * (1.0f / 256.0f);
    }
}

extern "C" void kernel_launch(void* const* d_in, const int* in_sizes, int n_in,
                              void* d_out, int out_size, void* d_ws, size_t ws_size,
                              hipStream_t stream) {
    const float* ploc   = (const float*)d_in[0];
    const float* plabel = (const float*)d_in[1];
    const float* gloc   = (const float*)d_in[2];
    const int*   glabel = (const int*)d_in[3];
    const float* dboxes = (const float*)d_in[4];
    float* ws  = (float*)d_ws;
    float* out = (float*)d_out;

    dim3 grid(N_ROWS, CHUNKS);
    hipLaunchKernelGGL(partial_kernel, grid, dim3(256), 0, stream,
                       ploc, plabel, gloc, glabel, dboxes, ws);
    hipLaunchKernelGGL(final_kernel, dim3(1), dim3(256), 0, stream,
                       ws, plabel, glabel, out);
}

// Round 2
// 24.015 us; speedup vs baseline: 1.1272x; 1.1272x over previous
//
#include <hip/hip_runtime.h>
#include <math.h>

#define N_ROWS 256
#define NB 8732
#define NB4 2183          // NB / 4 (exact)
#define CHUNKS 8
#define G_PER_CHUNK 273   // ceil(NB4 / CHUNKS) ; 273*8 = 2184 >= 2183

typedef float f4 __attribute__((ext_vector_type(4)));
typedef int   i4 __attribute__((ext_vector_type(4)));

__device__ __forceinline__ float smooth_l1(float d) {
    float ad = fabsf(d);
    return ad < 1.0f ? 0.5f * d * d : ad - 0.5f;
}

// BCE with logits, y = 0 (used by fallback top-K path only; accurate version)
__device__ __forceinline__ float bce_y0(float x) {
    return fmaxf(x, 0.0f) + log1pf(expf(-fabsf(x)));
}

__global__ __launch_bounds__(256) void partial_kernel(
    const float* __restrict__ ploc, const float* __restrict__ plabel,
    const float* __restrict__ gloc, const int* __restrict__ glabel,
    const float* __restrict__ dboxes, float* __restrict__ ws) {
    const int row = blockIdx.x;
    const int chunk = blockIdx.y;
    const int tid = threadIdx.x;

    const int g0 = chunk * G_PER_CHUNK;
    const int g1 = min(g0 + G_PER_CHUNK, NB4);

    const f4* __restrict__ ploc4 = (const f4*)ploc;
    const f4* __restrict__ gloc4 = (const f4*)gloc;
    const f4* __restrict__ db4   = (const f4*)dboxes;
    const f4* __restrict__ pl4   = (const f4*)plabel;
    const i4* __restrict__ gl4   = (const i4*)glabel;

    const int rb = row * 4 * NB4;  // base (float4 units) for [N,4,NB] tensors
    const int rs = row * NB4;      // base (float4 units) for [N,NB] tensors

    float sl1acc = 0.0f, conAll = 0.0f, conPos = 0.0f;
    float posCnt = 0.0f;

    for (int g = g0 + tid; g < g1; g += 256) {
        f4 p0 = __builtin_nontemporal_load(&ploc4[rb + 0 * NB4 + g]);
        f4 p1 = __builtin_nontemporal_load(&ploc4[rb + 1 * NB4 + g]);
        f4 p2 = __builtin_nontemporal_load(&ploc4[rb + 2 * NB4 + g]);
        f4 p3 = __builtin_nontemporal_load(&ploc4[rb + 3 * NB4 + g]);
        f4 q0 = __builtin_nontemporal_load(&gloc4[rb + 0 * NB4 + g]);
        f4 q1 = __builtin_nontemporal_load(&gloc4[rb + 1 * NB4 + g]);
        f4 q2 = __builtin_nontemporal_load(&gloc4[rb + 2 * NB4 + g]);
        f4 q3 = __builtin_nontemporal_load(&gloc4[rb + 3 * NB4 + g]);
        f4 d0 = db4[0 * NB4 + g];   // dboxes: shared across rows, keep cached
        f4 d1 = db4[1 * NB4 + g];
        f4 d2 = db4[2 * NB4 + g];
        f4 d3 = db4[3 * NB4 + g];
        i4 lb = __builtin_nontemporal_load(&gl4[rs + g]);
        f4 px = __builtin_nontemporal_load(&pl4[rs + g]);

#pragma unroll
        for (int k = 0; k < 4; ++k) {
            float rw2 = __builtin_amdgcn_rcpf(d2[k]);
            float rw3 = __builtin_amdgcn_rcpf(d3[k]);
            float gx = (q0[k] - d0[k]) * rw2;
            float gy = (q1[k] - d1[k]) * rw3;
            float gw = __logf(q2[k] * rw2);
            float gh = __logf(q3[k] * rw3);
            float s = smooth_l1(p0[k] - gx)
                    + smooth_l1(p1[k] - gy)
                    + smooth_l1(p2[k] - gw)
                    + smooth_l1(p3[k] - gh);
            int lab = lb[k];
            float x = px[k];
            float con = fmaxf(x, 0.0f) - x * (float)lab
                      + __logf(1.0f + __expf(-fabsf(x)));
            conAll += con;
            float m = (lab > 0) ? 1.0f : 0.0f;
            posCnt += m;
            sl1acc += m * s;
            conPos += m * con;
        }
    }

    // block reduction: wave64 shuffle, then LDS across 4 waves
    float v0 = sl1acc, v1 = conAll, v2 = conPos, v3 = posCnt;
#pragma unroll
    for (int off = 32; off > 0; off >>= 1) {
        v0 += __shfl_down(v0, off);
        v1 += __shfl_down(v1, off);
        v2 += __shfl_down(v2, off);
        v3 += __shfl_down(v3, off);
    }
    __shared__ float sm[4][4];
    const int wid = tid >> 6, lane = tid & 63;
    if (lane == 0) {
        sm[wid][0] = v0; sm[wid][1] = v1; sm[wid][2] = v2; sm[wid][3] = v3;
    }
    __syncthreads();
    if (tid == 0) {
        float a0 = 0.f, a1 = 0.f, a2 = 0.f, a3 = 0.f;
#pragma unroll
        for (int w = 0; w < 4; ++w) {
            a0 += sm[w][0]; a1 += sm[w][1]; a2 += sm[w][2]; a3 += sm[w][3];
        }
        float* o = ws + (row * CHUNKS + chunk) * 4;
        o[0] = a0; o[1] = a1; o[2] = a2; o[3] = a3;
    }
}

__global__ __launch_bounds__(256) void final_kernel(
    const float* __restrict__ ws, const float* __restrict__ plabel,
    const int* __restrict__ glabel, float* __restrict__ out) {
    const int row = threadIdx.x;  // one thread per batch row
    float sl1 = 0.f, conAll = 0.f, conPos = 0.f, posf = 0.f;
#pragma unroll
    for (int c = 0; c < CHUNKS; ++c) {
        const float* p = ws + (row * CHUNKS + c) * 4;
        sl1 += p[0]; conAll += p[1]; conPos += p[2]; posf += p[3];
    }
    const int pos = (int)(posf + 0.5f);
    const long long K = 3LL * (long long)pos;

    float closs;
    if (pos == 0) {
        closs = 0.0f;
    } else if (K >= (long long)NB) {
        // neg_mask selects every position -> keep everything
        closs = conAll;
    } else {
        // General hard-negative-mining fallback (dead for this data):
        // top-K negative con values via radix binary search on the uint
        // bit pattern (all con >= 0, so uint order == float order).
        const int Ki = (int)K;
        const float* plRow = plabel + row * NB;
        const int* glRow = glabel + row * NB;
        unsigned cur = 0;
        for (int bit = 31; bit >= 0; --bit) {
            unsigned trial = cur | (1u << bit);
            int cnt = 0;
            for (int j = 0; j < NB; ++j) {
                if (glRow[j] > 0) continue;
                float con = bce_y0(plRow[j]);
                if (__float_as_uint(con) >= trial) cnt++;
            }
            if (cnt >= Ki) cur = trial;
        }
        const float thr = __uint_as_float(cur);
        int cntG = 0; float sumG = 0.f;
        for (int j = 0; j < NB; ++j) {
            if (glRow[j] > 0) continue;
            float con = bce_y0(plRow[j]);
            if (con > thr) { cntG++; sumG += con; }
        }
        closs = conPos + sumG + (float)(Ki - cntG) * thr;
    }

    float loss = (pos > 0) ? (sl1 + closs) / (float)pos : 0.0f;

    // mean over 256 rows
#pragma unroll
    for (int off = 32; off > 0; off >>= 1) loss += __shfl_down(loss, off);
    __shared__ float sm[4];
    const int wid = threadIdx.x >> 6, lane = threadIdx.x & 63;
    if (lane == 0) sm[wid] = loss;
    __syncthreads();
    if (threadIdx.x == 0) {
        float t = sm[0] + sm[1] + sm[2] + sm[3];
        out[0] = t * (1.0f / 256.0f);
    }
}

extern "C" void kernel_launch(void* const* d_in, const int* in_sizes, int n_in,
                              void* d_out, int out_size, void* d_ws, size_t ws_size,
                              hipStream_t stream) {
    const float* ploc   = (const float*)d_in[0];
    const float* plabel = (const float*)d_in[1];
    const float* gloc   = (const float*)d_in[2];
    const int*   glabel = (const int*)d_in[3];
    const float* dboxes = (const float*)d_in[4];
    float* ws  = (float*)d_ws;
    float* out = (float*)d_out;

    dim3 grid(N_ROWS, CHUNKS);
    hipLaunchKernelGGL(partial_kernel, grid, dim3(256), 0, stream,
                       ploc, plabel, gloc, glabel, dboxes, ws);
    hipLaunchKernelGGL(final_kernel, dim3(1), dim3(256), 0, stream,
                       ws, plabel, glabel, out);
}